// Round 10
// baseline (121.429 us; speedup 1.0000x reference)
//
#include <hip/hip_runtime.h>
#include <math.h>

#define SLOPE 0.01f
#define CHUNK_SHIFT 13
#define CHUNK_SZ (1 << CHUNK_SHIFT)
#define MAXWORDS 12544   // supports n_nodes <= 50176 (problem: 50000)

using bf16x8 = __attribute__((ext_vector_type(8))) short;
using f32x4  = __attribute__((ext_vector_type(4))) float;

__device__ __forceinline__ unsigned short f2bf(float f) {
  unsigned int u = __float_as_uint(f);
  unsigned int r = 0x7FFFu + ((u >> 16) & 1u);
  return (unsigned short)((u + r) >> 16);
}
__device__ __forceinline__ float bflo(unsigned int v) {
  return __uint_as_float(v << 16);
}
__device__ __forceinline__ float bfhi(unsigned int v) {
  return __uint_as_float(v & 0xFFFF0000u);
}
__device__ __forceinline__ bf16x8 pack8(float4 a, float4 b) {
  bf16x8 r;
  r[0] = (short)f2bf(a.x); r[1] = (short)f2bf(a.y);
  r[2] = (short)f2bf(a.z); r[3] = (short)f2bf(a.w);
  r[4] = (short)f2bf(b.x); r[5] = (short)f2bf(b.y);
  r[6] = (short)f2bf(b.z); r[7] = (short)f2bf(b.w);
  return r;
}

// ---------------------------------------------------------------
// prep: fused conv_w | crel (2 rel/block)   (no more deg zeroing)
// ---------------------------------------------------------------
__global__ __launch_bounds__(256) void prep(
    const float* __restrict__ W1, unsigned short* __restrict__ WT, int B1,
    const float* __restrict__ rel, const float* __restrict__ b1,
    const float* __restrict__ w2,
    unsigned short* __restrict__ Crelbf, float* __restrict__ pC, int n_rel) {
  int b = blockIdx.x;
  int tid = threadIdx.x;
  if (b < B1) {
    int idx = b * 256 + tid;   // 32768 over 128 blocks
    int n = idx >> 7, k = idx & 127;
    int src_row = ((n >> 7) << 7) + k;
    WT[n * 128 + k] = f2bf(W1[src_row * 128 + (n & 127)]);
  } else {
    __shared__ float rs[2][128];
    __shared__ float red[2][128];
    int h = tid >> 7, d = tid & 127;
    int r = (b - B1) * 2 + h;
    bool valid = r < n_rel;
    rs[h][d] = valid ? rel[r * 128 + d] : 0.f;
    __syncthreads();
    float acc = b1[d];
    for (int k = 0; k < 128; ++k)
      acc = fmaf(rs[h][k], W1[(256 + k) * 128 + d], acc);
    if (valid) Crelbf[r * 128 + d] = f2bf(acc);
    red[h][d] = acc * w2[d];
    __syncthreads();
    for (int s = 64; s > 0; s >>= 1) {
      if (d < s) red[h][d] += red[h][d + s];
      __syncthreads();
    }
    if (d == 0 && valid) pC[r] = red[h][0];
  }
}

// ---------------------------------------------------------------
// msplitA: per-chunk LDS histogram (uint8 packed 4/word) + local rank.
// Block c handles edges [c*8192, (c+1)*8192). ZERO global atomics.
// ---------------------------------------------------------------
__global__ __launch_bounds__(1024) void msplitA(
    const int* __restrict__ dsts, unsigned int* __restrict__ cntg,
    unsigned char* __restrict__ rank8, int E, int words) {
  __shared__ unsigned int lcnt[MAXWORDS];
  int t = threadIdx.x;
  int c = blockIdx.x;
  for (int w = t; w < words; w += 1024) lcnt[w] = 0;
  __syncthreads();
  int base = c << CHUNK_SHIFT;
  int lim = E - base; if (lim > CHUNK_SZ) lim = CHUNK_SZ;
  for (int k = t; k < lim; k += 1024) {
    int dn = dsts[base + k];
    unsigned int sh = 8u * (dn & 3);
    unsigned int old = atomicAdd(&lcnt[dn >> 2], 1u << sh);
    rank8[base + k] = (unsigned char)((old >> sh) & 0xFFu);
  }
  __syncthreads();
  unsigned int* dstp = cntg + (size_t)c * words;
  for (int w = t; w < words; w += 1024) dstp[w] = lcnt[w];
}

// ---------------------------------------------------------------
// msplitB + scan1 fused: node-parallel chunk-prefix (p16), deg,
// then block-local exclusive scan of deg -> off, partial.
// ---------------------------------------------------------------
__global__ __launch_bounds__(1024) void msplitB_scan1(
    const unsigned int* __restrict__ cntg, unsigned short* __restrict__ p16,
    int* __restrict__ deg, int* __restrict__ off, int* __restrict__ partial,
    int n, int words, int C) {
  __shared__ int sdata[1024];
  int t = threadIdx.x;
  int i = blockIdx.x * 1024 + t;
  int run = 0;
  if (i < n) {
    int w = i >> 2, sh = 8 * (i & 3);
    for (int c = 0; c < C; ++c) {
      unsigned int cw = cntg[(size_t)c * words + w];
      p16[(size_t)c * n + i] = (unsigned short)run;
      run += (int)((cw >> sh) & 0xFFu);
    }
    deg[i] = run;
  }
  int v = (i < n) ? run : 0;
  sdata[t] = v;
  __syncthreads();
  for (int s = 1; s < 1024; s <<= 1) {
    int add = (t >= s) ? sdata[t - s] : 0;
    __syncthreads();
    sdata[t] += add;
    __syncthreads();
  }
  if (i < n) off[i] = sdata[t] - v;
  if (t == 1023) partial[blockIdx.x] = sdata[1023];
}

__global__ __launch_bounds__(1024) void scan3(
    int* __restrict__ off, const int* __restrict__ partial, int n, int nb) {
  __shared__ int carry_s;
  int t = threadIdx.x;
  if (t < 64) {
    int v = (t < nb) ? partial[t] : 0;
    for (int s = 1; s < 64; s <<= 1) {
      int u = __shfl_up(v, s, 64);
      if ((t & 63) >= s) v += u;
    }
    int b = blockIdx.x;
    int c = __shfl(v, b - 1, 64);
    if (t == 0) carry_s = (b == 0) ? 0 : c;
  }
  __syncthreads();
  int i = blockIdx.x * 1024 + t;
  if (i < n) off[i] += carry_s;
}

// ---------------------------------------------------------------
// Pure MFMA GEMM: [A|B] = bf16(x) @ WT^T. Block = 64M x 256N, 4 waves
// (2m x 2n), wave = 32M x 128N. A,B stored bf16; fused pA/pB dot-w2.
// ---------------------------------------------------------------
__global__ __launch_bounds__(256) void gemm_mfma(
    const float* __restrict__ x, const unsigned short* __restrict__ WT,
    const float* __restrict__ w2,
    unsigned short* __restrict__ Abf, unsigned short* __restrict__ Bmbf,
    float* __restrict__ pA, float* __restrict__ pB, int M) {
  int tid  = threadIdx.x;
  int wave = tid >> 6, lane = tid & 63;
  int wm = wave >> 1, wn = wave & 1;
  int l15 = lane & 15, l4 = lane >> 4;
  int m0 = blockIdx.x * 64;

  f32x4 acc[2][8];
  #pragma unroll
  for (int mi = 0; mi < 2; ++mi)
    #pragma unroll
    for (int ni = 0; ni < 8; ++ni) acc[mi][ni] = (f32x4){0.f, 0.f, 0.f, 0.f};

  int arow0 = m0 + wm * 32 + l15;
  int arow1 = arow0 + 16;
  int ar0 = arow0 < M ? arow0 : M - 1;
  int ar1 = arow1 < M ? arow1 : M - 1;
  const float* xbase0 = x + (size_t)ar0 * 128 + l4 * 8;
  const float* xbase1 = x + (size_t)ar1 * 128 + l4 * 8;
  const unsigned short* bbase = WT + (size_t)(wn * 128 + l15) * 128 + l4 * 8;

  #pragma unroll
  for (int ks = 0; ks < 4; ++ks) {
    float4 a0lo = *(const float4*)(xbase0 + ks * 32);
    float4 a0hi = *(const float4*)(xbase0 + ks * 32 + 4);
    float4 a1lo = *(const float4*)(xbase1 + ks * 32);
    float4 a1hi = *(const float4*)(xbase1 + ks * 32 + 4);
    bf16x8 af0 = pack8(a0lo, a0hi);
    bf16x8 af1 = pack8(a1lo, a1hi);
    #pragma unroll
    for (int ni = 0; ni < 8; ++ni) {
      bf16x8 bf = *(const bf16x8*)(bbase + ni * 16 * 128 + ks * 32);
      acc[0][ni] = __builtin_amdgcn_mfma_f32_16x16x32_bf16(af0, bf, acc[0][ni], 0, 0, 0);
      acc[1][ni] = __builtin_amdgcn_mfma_f32_16x16x32_bf16(af1, bf, acc[1][ni], 0, 0, 0);
    }
  }

  unsigned short* dstp = (wn == 0) ? Abf : Bmbf;
  #pragma unroll
  for (int mi = 0; mi < 2; ++mi) {
    #pragma unroll
    for (int ni = 0; ni < 8; ++ni) {
      int coll = ni * 16 + l15;
      #pragma unroll
      for (int r = 0; r < 4; ++r) {
        int row = m0 + wm * 32 + mi * 16 + l4 * 4 + r;
        if (row < M) dstp[(size_t)row * 128 + coll] = f2bf(acc[mi][ni][r]);
      }
    }
  }

  float w2c[8];
  #pragma unroll
  for (int ni = 0; ni < 8; ++ni) w2c[ni] = w2[ni * 16 + l15];
  float* pdst = (wn == 0) ? pA : pB;
  #pragma unroll
  for (int mi = 0; mi < 2; ++mi) {
    #pragma unroll
    for (int r = 0; r < 4; ++r) {
      float v = 0.f;
      #pragma unroll
      for (int ni = 0; ni < 8; ++ni) v = fmaf(acc[mi][ni][r], w2c[ni], v);
      v += __shfl_xor(v, 1, 64);
      v += __shfl_xor(v, 2, 64);
      v += __shfl_xor(v, 4, 64);
      v += __shfl_xor(v, 8, 64);
      if (l15 == 0) {
        int row = m0 + wm * 32 + mi * 16 + l4 * 4 + r;
        if (row < M) pdst[row] = v;
      }
    }
  }
}

// ---------------------------------------------------------------
// fill CSR slots, fully atomic-free:
// slot = off[dst] + p16[chunk][dst] + rank8[e]
// ---------------------------------------------------------------
__global__ void fill_perm(
    const int* __restrict__ srcs, const int* __restrict__ dsts,
    const int* __restrict__ types, const unsigned char* __restrict__ rank8,
    const int* __restrict__ off, const unsigned short* __restrict__ p16,
    unsigned int* __restrict__ stperm, int E, int n) {
  int i = blockIdx.x * 256 + threadIdx.x;
  if (i < E) {
    int dn = dsts[i];
    int c = i >> CHUNK_SHIFT;
    int p = off[dn] + (int)p16[(size_t)c * n + dn] + (int)rank8[i];
    stperm[p] = (unsigned int)srcs[i] | ((unsigned int)types[i] << 16);
  }
}

// ---------------------------------------------------------------
// Single-pass per-node shift-free softmax + weighted bf16 gather.
// ---------------------------------------------------------------
__global__ __launch_bounds__(256) void aggregate(
    const int* __restrict__ off, const int* __restrict__ deg,
    const unsigned int* __restrict__ stperm,
    const float* __restrict__ pA, const float* __restrict__ pB,
    const float* __restrict__ pCg,
    const unsigned short* __restrict__ Abf,
    const unsigned short* __restrict__ Bmbf,
    const unsigned short* __restrict__ Crelbf,
    float* __restrict__ out, int n_nodes, int n_rel) {
  __shared__ float pCs[256];
  for (int r = threadIdx.x; r < n_rel; r += 256) pCs[r] = pCg[r];
  __syncthreads();
  int n = blockIdx.x * 4 + (threadIdx.x >> 6);
  if (n >= n_nodes) return;
  int lane = threadIdx.x & 63;
  int start = off[n];
  int dcnt = deg[n];
  size_t obase = (size_t)n * 128 + 2 * lane;
  if (dcnt == 0) {
    *(float2*)(out + obase) = (float2){0.f, 0.f};
    return;
  }
  float pBn = pB[n];
  float acc0 = 0.f, acc1 = 0.f, S = 0.f;
  int cl2 = 2 * lane;
  int i = 0;
  for (; i + 4 <= dcnt; i += 4) {
    unsigned int st[4];
    #pragma unroll
    for (int j = 0; j < 4; ++j) st[j] = stperm[start + i + j];
    unsigned int av[4], cv[4];
    float pa[4];
    #pragma unroll
    for (int j = 0; j < 4; ++j) {
      unsigned int s = st[j] & 0xFFFFu, t = st[j] >> 16;
      av[j] = *(const unsigned int*)(Abf + ((size_t)s << 7) + cl2);
      cv[j] = *(const unsigned int*)(Crelbf + (t << 7) + cl2);
      pa[j] = pA[s];
    }
    #pragma unroll
    for (int j = 0; j < 4; ++j) {
      float b = pa[j] + pBn + pCs[st[j] >> 16];
      b = b > 0.f ? b : SLOPE * b;
      float ex = __expf(b);
      S += ex;
      acc0 = fmaf(ex, bflo(av[j]) + bflo(cv[j]), acc0);
      acc1 = fmaf(ex, bfhi(av[j]) + bfhi(cv[j]), acc1);
    }
  }
  for (; i < dcnt; ++i) {
    unsigned int st = stperm[start + i];
    unsigned int s = st & 0xFFFFu, t = st >> 16;
    unsigned int av = *(const unsigned int*)(Abf + ((size_t)s << 7) + cl2);
    unsigned int cv = *(const unsigned int*)(Crelbf + (t << 7) + cl2);
    float b = pA[s] + pBn + pCs[t];
    b = b > 0.f ? b : SLOPE * b;
    float ex = __expf(b);
    S += ex;
    acc0 = fmaf(ex, bflo(av) + bflo(cv), acc0);
    acc1 = fmaf(ex, bfhi(av) + bfhi(cv), acc1);
  }
  float inv = 1.f / S;
  unsigned int bm = *(const unsigned int*)(Bmbf + obase);
  float o0 = acc0 * inv + bflo(bm);
  float o1 = acc1 * inv + bfhi(bm);
  o0 = o0 > 0.f ? o0 : SLOPE * o0;
  o1 = o1 > 0.f ? o1 : SLOPE * o1;
  *(float2*)(out + obase) = (float2){o0, o1};
}

extern "C" void kernel_launch(void* const* d_in, const int* in_sizes, int n_in,
                              void* d_out, int out_size, void* d_ws, size_t ws_size,
                              hipStream_t stream) {
  const float* x    = (const float*)d_in[0];
  const float* rel  = (const float*)d_in[1];
  const float* W1   = (const float*)d_in[2];
  const float* b1   = (const float*)d_in[3];
  const float* w2   = (const float*)d_in[4];
  const int* edge_index = (const int*)d_in[5];
  const int* edge_type  = (const int*)d_in[6];

  int n_nodes = in_sizes[0] / 128;
  int n_rel   = in_sizes[1] / 128;
  int E       = in_sizes[6];
  const int* srcs = edge_index;
  const int* dsts = edge_index + E;
  float* out = (float*)d_out;

  int words = (n_nodes + 3) >> 2;         // <= MAXWORDS for this problem
  int C     = (E + CHUNK_SZ - 1) >> CHUNK_SHIFT;

  auto align256 = [](size_t v) { return (v + 255) & ~(size_t)255; };
  char* ws = (char*)d_ws;
  unsigned short* WT     = (unsigned short*)ws; ws += align256(256 * 128 * 2);
  unsigned short* Abf    = (unsigned short*)ws; ws += align256((size_t)n_nodes * 128 * 2);
  unsigned short* Bmbf   = (unsigned short*)ws; ws += align256((size_t)n_nodes * 128 * 2);
  unsigned short* Crelbf = (unsigned short*)ws; ws += align256((size_t)n_rel * 128 * 2);
  float* pA    = (float*)ws; ws += align256((size_t)n_nodes * 4);
  float* pB    = (float*)ws; ws += align256((size_t)n_nodes * 4);
  float* pC    = (float*)ws; ws += align256((size_t)n_rel * 4);
  int* deg     = (int*)ws;   ws += align256((size_t)n_nodes * 4);
  int* off     = (int*)ws;   ws += align256((size_t)n_nodes * 4);
  int* partial = (int*)ws;   ws += align256(1024 * 4);
  unsigned int* cntg = (unsigned int*)ws;   ws += align256((size_t)C * words * 4);
  unsigned short* p16 = (unsigned short*)ws; ws += align256((size_t)C * n_nodes * 2);
  unsigned char* rank8 = (unsigned char*)ws; ws += align256((size_t)E);
  unsigned int* stperm = (unsigned int*)ws;  ws += align256((size_t)E * 4);

  int B1 = 128;                           // conv_w blocks
  int B2 = B1 + (n_rel + 1) / 2;          // + crel blocks
  prep<<<B2, 256, 0, stream>>>(W1, WT, B1, rel, b1, w2, Crelbf, pC, n_rel);

  msplitA<<<C, 1024, 0, stream>>>(dsts, cntg, rank8, E, words);

  gemm_mfma<<<(n_nodes + 63) / 64, 256, 0, stream>>>(
      x, WT, w2, Abf, Bmbf, pA, pB, n_nodes);

  int nb = (n_nodes + 1023) / 1024;       // must be <= 64
  msplitB_scan1<<<nb, 1024, 0, stream>>>(cntg, p16, deg, off, partial,
                                         n_nodes, words, C);
  scan3<<<nb, 1024, 0, stream>>>(off, partial, n_nodes, nb);

  fill_perm<<<(E + 255) / 256, 256, 0, stream>>>(
      srcs, dsts, edge_type, rank8, off, p16, stperm, E, n_nodes);

  aggregate<<<(n_nodes + 3) / 4, 256, 0, stream>>>(
      off, deg, stperm, pA, pB, pC, Abf, Bmbf, Crelbf, out, n_nodes, n_rel);
}

// Round 11
// 106.708 us; speedup vs baseline: 1.1379x; 1.1379x over previous
//
#include <hip/hip_runtime.h>
#include <math.h>

#define SLOPE 0.01f
#define CHUNK_SHIFT 13
#define CHUNK_SZ (1 << CHUNK_SHIFT)
#define MAXWORDS 12544   // supports n_nodes <= 50176 (problem: 50000)
#define LWT_STRIDE 136   // padded row stride (shorts): 16B-aligned, ~2-way banks

using bf16x8 = __attribute__((ext_vector_type(8))) short;
using f32x4  = __attribute__((ext_vector_type(4))) float;

__device__ __forceinline__ unsigned short f2bf(float f) {
  unsigned int u = __float_as_uint(f);
  unsigned int r = 0x7FFFu + ((u >> 16) & 1u);
  return (unsigned short)((u + r) >> 16);
}
__device__ __forceinline__ float bflo(unsigned int v) {
  return __uint_as_float(v << 16);
}
__device__ __forceinline__ float bfhi(unsigned int v) {
  return __uint_as_float(v & 0xFFFF0000u);
}
__device__ __forceinline__ bf16x8 pack8(float4 a, float4 b) {
  bf16x8 r;
  r[0] = (short)f2bf(a.x); r[1] = (short)f2bf(a.y);
  r[2] = (short)f2bf(a.z); r[3] = (short)f2bf(a.w);
  r[4] = (short)f2bf(b.x); r[5] = (short)f2bf(b.y);
  r[6] = (short)f2bf(b.z); r[7] = (short)f2bf(b.w);
  return r;
}

// ---------------------------------------------------------------
// MEGA dispatch 1: msplitA | crel | gemm (all mutually independent).
// msplitA blocks first (feed the critical path).
// gemm blocks self-transpose W1 -> LDS bf16 (no prep dependency).
// ---------------------------------------------------------------
__global__ __launch_bounds__(256) void mega(
    const float* __restrict__ x, const float* __restrict__ W1,
    const float* __restrict__ rel, const float* __restrict__ b1,
    const float* __restrict__ w2, const int* __restrict__ dsts,
    unsigned int* __restrict__ cntg, unsigned char* __restrict__ rank8,
    int E, int words,
    unsigned short* __restrict__ Crelbf, float* __restrict__ pC, int n_rel,
    unsigned short* __restrict__ Abf, unsigned short* __restrict__ Bmbf,
    float* __restrict__ pA, float* __restrict__ pB, int M,
    int CB, int RB) {
  __shared__ __align__(16) char smem_raw[256 * LWT_STRIDE * 2]; // 69632 B
  int b = blockIdx.x;
  int tid = threadIdx.x;

  if (b < CB) {
    // ---- msplitA: per-chunk LDS histogram + local rank, zero global atomics
    unsigned int* lcnt = (unsigned int*)smem_raw;
    for (int w = tid; w < words; w += 256) lcnt[w] = 0;
    __syncthreads();
    int base = b << CHUNK_SHIFT;
    int lim = E - base; if (lim > CHUNK_SZ) lim = CHUNK_SZ;
    for (int k = tid; k < lim; k += 256) {
      int dn = dsts[base + k];
      unsigned int sh = 8u * (dn & 3);
      unsigned int old = atomicAdd(&lcnt[dn >> 2], 1u << sh);
      rank8[base + k] = (unsigned char)((old >> sh) & 0xFFu);
    }
    __syncthreads();
    unsigned int* dstp = cntg + (size_t)b * words;
    for (int w = tid; w < words; w += 256) dstp[w] = lcnt[w];
    return;
  }

  if (b < RB) {
    // ---- crel: Crel[r] = rel[r] @ W1[256:384,:] + b1 (bf16); pC = Crel.w2
    float* rs  = (float*)smem_raw;        // [2][128]
    float* red = rs + 256;                // [2][128]
    int h = tid >> 7, d = tid & 127;
    int r = (b - CB) * 2 + h;
    bool valid = r < n_rel;
    rs[h * 128 + d] = valid ? rel[r * 128 + d] : 0.f;
    __syncthreads();
    float acc = b1[d];
    for (int k = 0; k < 128; ++k)
      acc = fmaf(rs[h * 128 + k], W1[(256 + k) * 128 + d], acc);
    if (valid) Crelbf[r * 128 + d] = f2bf(acc);
    red[h * 128 + d] = acc * w2[d];
    __syncthreads();
    for (int s = 64; s > 0; s >>= 1) {
      if (d < s) red[h * 128 + d] += red[h * 128 + d + s];
      __syncthreads();
    }
    if (d == 0 && valid) pC[r] = red[h * 128];
    return;
  }

  // ---- gemm: [A|B] = bf16(x) @ WT^T, WT built in LDS from W1
  unsigned short* lWT = (unsigned short*)smem_raw;  // [256][LWT_STRIDE]
  for (int i = tid; i < 32768; i += 256) {
    int r = i >> 7, c = i & 127;
    float v = W1[r * 128 + c];
    int n = c | ((r >> 7) << 7);   // output column index 0..255
    int k = r & 127;               // k index
    lWT[n * LWT_STRIDE + k] = f2bf(v);
  }
  __syncthreads();

  int wave = tid >> 6, lane = tid & 63;
  int wm = wave >> 1, wn = wave & 1;
  int l15 = lane & 15, l4 = lane >> 4;
  int m0 = (b - RB) * 64;

  f32x4 acc[2][8];
  #pragma unroll
  for (int mi = 0; mi < 2; ++mi)
    #pragma unroll
    for (int ni = 0; ni < 8; ++ni) acc[mi][ni] = (f32x4){0.f, 0.f, 0.f, 0.f};

  int arow0 = m0 + wm * 32 + l15;
  int arow1 = arow0 + 16;
  int ar0 = arow0 < M ? arow0 : M - 1;
  int ar1 = arow1 < M ? arow1 : M - 1;
  const float* xbase0 = x + (size_t)ar0 * 128 + l4 * 8;
  const float* xbase1 = x + (size_t)ar1 * 128 + l4 * 8;
  const unsigned short* bb = lWT + (wn * 128 + l15) * LWT_STRIDE + l4 * 8;

  #pragma unroll
  for (int ks = 0; ks < 4; ++ks) {
    float4 a0lo = *(const float4*)(xbase0 + ks * 32);
    float4 a0hi = *(const float4*)(xbase0 + ks * 32 + 4);
    float4 a1lo = *(const float4*)(xbase1 + ks * 32);
    float4 a1hi = *(const float4*)(xbase1 + ks * 32 + 4);
    bf16x8 af0 = pack8(a0lo, a0hi);
    bf16x8 af1 = pack8(a1lo, a1hi);
    #pragma unroll
    for (int ni = 0; ni < 8; ++ni) {
      bf16x8 bf = *(const bf16x8*)(bb + ni * 16 * LWT_STRIDE + ks * 32);
      acc[0][ni] = __builtin_amdgcn_mfma_f32_16x16x32_bf16(af0, bf, acc[0][ni], 0, 0, 0);
      acc[1][ni] = __builtin_amdgcn_mfma_f32_16x16x32_bf16(af1, bf, acc[1][ni], 0, 0, 0);
    }
  }

  unsigned short* dstp = (wn == 0) ? Abf : Bmbf;
  #pragma unroll
  for (int mi = 0; mi < 2; ++mi) {
    #pragma unroll
    for (int ni = 0; ni < 8; ++ni) {
      int coll = ni * 16 + l15;
      #pragma unroll
      for (int r = 0; r < 4; ++r) {
        int row = m0 + wm * 32 + mi * 16 + l4 * 4 + r;
        if (row < M) dstp[(size_t)row * 128 + coll] = f2bf(acc[mi][ni][r]);
      }
    }
  }

  float w2c[8];
  #pragma unroll
  for (int ni = 0; ni < 8; ++ni) w2c[ni] = w2[ni * 16 + l15];
  float* pdst = (wn == 0) ? pA : pB;
  #pragma unroll
  for (int mi = 0; mi < 2; ++mi) {
    #pragma unroll
    for (int r = 0; r < 4; ++r) {
      float v = 0.f;
      #pragma unroll
      for (int ni = 0; ni < 8; ++ni) v = fmaf(acc[mi][ni][r], w2c[ni], v);
      v += __shfl_xor(v, 1, 64);
      v += __shfl_xor(v, 2, 64);
      v += __shfl_xor(v, 4, 64);
      v += __shfl_xor(v, 8, 64);
      if (l15 == 0) {
        int row = m0 + wm * 32 + mi * 16 + l4 * 4 + r;
        if (row < M) pdst[row] = v;
      }
    }
  }
}

// ---------------------------------------------------------------
// msplitB + scan1 fused: node-parallel chunk-prefix (p16), deg,
// block-local exclusive scan of deg -> off (block-local), partial.
// ---------------------------------------------------------------
__global__ __launch_bounds__(1024) void msplitB_scan1(
    const unsigned int* __restrict__ cntg, unsigned short* __restrict__ p16,
    int* __restrict__ deg, int* __restrict__ off, int* __restrict__ partial,
    int n, int words, int C) {
  __shared__ int sdata[1024];
  int t = threadIdx.x;
  int i = blockIdx.x * 1024 + t;
  int run = 0;
  if (i < n) {
    int w = i >> 2, sh = 8 * (i & 3);
    for (int c = 0; c < C; ++c) {
      unsigned int cw = cntg[(size_t)c * words + w];
      p16[(size_t)c * n + i] = (unsigned short)run;
      run += (int)((cw >> sh) & 0xFFu);
    }
    deg[i] = run;
  }
  int v = (i < n) ? run : 0;
  sdata[t] = v;
  __syncthreads();
  for (int s = 1; s < 1024; s <<= 1) {
    int add = (t >= s) ? sdata[t - s] : 0;
    __syncthreads();
    sdata[t] += add;
    __syncthreads();
  }
  if (i < n) off[i] = sdata[t] - v;   // block-local exclusive
  if (t == 1023) partial[blockIdx.x] = sdata[1023];
}

// ---------------------------------------------------------------
// fill CSR slots, atomic-free, with INLINE carry prefix (no scan3):
// slot = off[dst] + carry[dst>>10] + p16[chunk][dst] + rank8[e]
// ---------------------------------------------------------------
__global__ __launch_bounds__(256) void fill_perm(
    const int* __restrict__ srcs, const int* __restrict__ dsts,
    const int* __restrict__ types, const unsigned char* __restrict__ rank8,
    const int* __restrict__ off, const int* __restrict__ partial, int nb,
    const unsigned short* __restrict__ p16,
    unsigned int* __restrict__ stperm, int E, int n) {
  __shared__ int carryLUT[64];
  int tid = threadIdx.x;
  if (tid < 64) {
    int v = (tid < nb) ? partial[tid] : 0;
    int inc = v;
    #pragma unroll
    for (int s = 1; s < 64; s <<= 1) {
      int u = __shfl_up(inc, s, 64);
      if (tid >= s) inc += u;
    }
    carryLUT[tid] = inc - v;   // exclusive prefix
  }
  __syncthreads();
  int i = blockIdx.x * 256 + tid;
  if (i < E) {
    int dn = dsts[i];
    int c = i >> CHUNK_SHIFT;
    int p = off[dn] + carryLUT[dn >> 10] + (int)p16[(size_t)c * n + dn] + (int)rank8[i];
    stperm[p] = (unsigned int)srcs[i] | ((unsigned int)types[i] << 16);
  }
}

// ---------------------------------------------------------------
// Aggregate: 2 nodes per wave (32 lanes x 4 cols each, uint2 gathers)
// -> doubled gather MLP. Inline carry prefix. Shift-free softmax.
// out[n] = lrelu( sum_e alpha_e (A[s]+Crel[t]) + B[n] )
// ---------------------------------------------------------------
__global__ __launch_bounds__(256) void aggregate(
    const int* __restrict__ off, const int* __restrict__ deg,
    const int* __restrict__ partial, int nb,
    const unsigned int* __restrict__ stperm,
    const float* __restrict__ pA, const float* __restrict__ pB,
    const float* __restrict__ pCg,
    const unsigned short* __restrict__ Abf,
    const unsigned short* __restrict__ Bmbf,
    const unsigned short* __restrict__ Crelbf,
    float* __restrict__ out, int n_nodes, int n_rel) {
  __shared__ float pCs[256];
  __shared__ int carryLUT[64];
  int tid = threadIdx.x;
  if (tid < 64) {
    int v = (tid < nb) ? partial[tid] : 0;
    int inc = v;
    #pragma unroll
    for (int s = 1; s < 64; s <<= 1) {
      int u = __shfl_up(inc, s, 64);
      if (tid >= s) inc += u;
    }
    carryLUT[tid] = inc - v;
  }
  for (int r = tid; r < n_rel; r += 256) pCs[r] = pCg[r];
  __syncthreads();

  int n = blockIdx.x * 8 + (tid >> 5);   // 8 nodes per block
  if (n >= n_nodes) return;
  int lane = tid & 31;
  int c4 = lane * 4;                      // 4 bf16 cols per lane
  int start = off[n] + carryLUT[n >> 10];
  int dcnt = deg[n];
  size_t obase = (size_t)n * 128 + c4;
  if (dcnt == 0) {
    *(float4*)(out + obase) = (float4){0.f, 0.f, 0.f, 0.f};
    return;
  }
  float pBn = pB[n];
  float acc0 = 0.f, acc1 = 0.f, acc2 = 0.f, acc3 = 0.f, S = 0.f;
  int i = 0;
  for (; i + 4 <= dcnt; i += 4) {
    unsigned int st[4];
    #pragma unroll
    for (int j = 0; j < 4; ++j) st[j] = stperm[start + i + j];
    uint2 av[4], cv[4];
    float pa[4];
    #pragma unroll
    for (int j = 0; j < 4; ++j) {
      unsigned int s = st[j] & 0xFFFFu, t = st[j] >> 16;
      av[j] = *(const uint2*)(Abf + ((size_t)s << 7) + c4);
      cv[j] = *(const uint2*)(Crelbf + (t << 7) + c4);
      pa[j] = pA[s];
    }
    #pragma unroll
    for (int j = 0; j < 4; ++j) {
      float b = pa[j] + pBn + pCs[st[j] >> 16];
      b = b > 0.f ? b : SLOPE * b;
      float ex = __expf(b);
      S += ex;
      acc0 = fmaf(ex, bflo(av[j].x) + bflo(cv[j].x), acc0);
      acc1 = fmaf(ex, bfhi(av[j].x) + bfhi(cv[j].x), acc1);
      acc2 = fmaf(ex, bflo(av[j].y) + bflo(cv[j].y), acc2);
      acc3 = fmaf(ex, bfhi(av[j].y) + bfhi(cv[j].y), acc3);
    }
  }
  for (; i < dcnt; ++i) {
    unsigned int st = stperm[start + i];
    unsigned int s = st & 0xFFFFu, t = st >> 16;
    uint2 av = *(const uint2*)(Abf + ((size_t)s << 7) + c4);
    uint2 cv = *(const uint2*)(Crelbf + (t << 7) + c4);
    float b = pA[s] + pBn + pCs[t];
    b = b > 0.f ? b : SLOPE * b;
    float ex = __expf(b);
    S += ex;
    acc0 = fmaf(ex, bflo(av.x) + bflo(cv.x), acc0);
    acc1 = fmaf(ex, bfhi(av.x) + bfhi(cv.x), acc1);
    acc2 = fmaf(ex, bflo(av.y) + bflo(cv.y), acc2);
    acc3 = fmaf(ex, bfhi(av.y) + bfhi(cv.y), acc3);
  }
  float inv = 1.f / S;
  uint2 bm = *(const uint2*)(Bmbf + obase);
  float o0 = acc0 * inv + bflo(bm.x);
  float o1 = acc1 * inv + bfhi(bm.x);
  float o2 = acc2 * inv + bflo(bm.y);
  float o3 = acc3 * inv + bfhi(bm.y);
  o0 = o0 > 0.f ? o0 : SLOPE * o0;
  o1 = o1 > 0.f ? o1 : SLOPE * o1;
  o2 = o2 > 0.f ? o2 : SLOPE * o2;
  o3 = o3 > 0.f ? o3 : SLOPE * o3;
  *(float4*)(out + obase) = (float4){o0, o1, o2, o3};
}

extern "C" void kernel_launch(void* const* d_in, const int* in_sizes, int n_in,
                              void* d_out, int out_size, void* d_ws, size_t ws_size,
                              hipStream_t stream) {
  const float* x    = (const float*)d_in[0];
  const float* rel  = (const float*)d_in[1];
  const float* W1   = (const float*)d_in[2];
  const float* b1   = (const float*)d_in[3];
  const float* w2   = (const float*)d_in[4];
  const int* edge_index = (const int*)d_in[5];
  const int* edge_type  = (const int*)d_in[6];

  int n_nodes = in_sizes[0] / 128;
  int n_rel   = in_sizes[1] / 128;
  int E       = in_sizes[6];
  const int* srcs = edge_index;
  const int* dsts = edge_index + E;
  float* out = (float*)d_out;

  int words = (n_nodes + 3) >> 2;
  int C     = (E + CHUNK_SZ - 1) >> CHUNK_SHIFT;

  auto align256 = [](size_t v) { return (v + 255) & ~(size_t)255; };
  char* ws = (char*)d_ws;
  unsigned short* Abf    = (unsigned short*)ws; ws += align256((size_t)n_nodes * 128 * 2);
  unsigned short* Bmbf   = (unsigned short*)ws; ws += align256((size_t)n_nodes * 128 * 2);
  unsigned short* Crelbf = (unsigned short*)ws; ws += align256((size_t)n_rel * 128 * 2);
  float* pA    = (float*)ws; ws += align256((size_t)n_nodes * 4);
  float* pB    = (float*)ws; ws += align256((size_t)n_nodes * 4);
  float* pC    = (float*)ws; ws += align256((size_t)n_rel * 4);
  int* deg     = (int*)ws;   ws += align256((size_t)n_nodes * 4);
  int* off     = (int*)ws;   ws += align256((size_t)n_nodes * 4);
  int* partial = (int*)ws;   ws += align256(1024 * 4);
  unsigned int* cntg = (unsigned int*)ws;    ws += align256((size_t)C * words * 4);
  unsigned short* p16 = (unsigned short*)ws; ws += align256((size_t)C * n_nodes * 2);
  unsigned char* rank8 = (unsigned char*)ws; ws += align256((size_t)E);
  unsigned int* stperm = (unsigned int*)ws;  ws += align256((size_t)E * 4);

  int CB = C;                       // msplitA blocks (first: critical path)
  int RB = CB + (n_rel + 1) / 2;    // + crel blocks
  int gB = (n_nodes + 63) / 64;     // + gemm blocks
  mega<<<RB + gB, 256, 0, stream>>>(
      x, W1, rel, b1, w2, dsts, cntg, rank8, E, words,
      Crelbf, pC, n_rel, Abf, Bmbf, pA, pB, n_nodes, CB, RB);

  int nb = (n_nodes + 1023) / 1024;   // must be <= 64
  msplitB_scan1<<<nb, 1024, 0, stream>>>(cntg, p16, deg, off, partial,
                                         n_nodes, words, C);

  fill_perm<<<(E + 255) / 256, 256, 0, stream>>>(
      srcs, dsts, edge_type, rank8, off, partial, nb, p16, stperm, E, n_nodes);

  aggregate<<<(n_nodes + 7) / 8, 256, 0, stream>>>(
      off, deg, partial, nb, stperm, pA, pB, pC, Abf, Bmbf, Crelbf,
      out, n_nodes, n_rel);
}

// Round 12
// 90.891 us; speedup vs baseline: 1.3360x; 1.1740x over previous
//
#include <hip/hip_runtime.h>
#include <math.h>

#define SLOPE 0.01f
#define CHUNK_SHIFT 13
#define CHUNK_SZ (1 << CHUNK_SHIFT)
#define MAXWORDS 12544   // supports n_nodes <= 50176 (problem: 50000)

using bf16x8 = __attribute__((ext_vector_type(8))) short;
using f32x4  = __attribute__((ext_vector_type(4))) float;

__device__ __forceinline__ unsigned short f2bf(float f) {
  unsigned int u = __float_as_uint(f);
  unsigned int r = 0x7FFFu + ((u >> 16) & 1u);
  return (unsigned short)((u + r) >> 16);
}
__device__ __forceinline__ float bflo(unsigned int v) {
  return __uint_as_float(v << 16);
}
__device__ __forceinline__ float bfhi(unsigned int v) {
  return __uint_as_float(v & 0xFFFF0000u);
}
__device__ __forceinline__ bf16x8 pack8(float4 a, float4 b) {
  bf16x8 r;
  r[0] = (short)f2bf(a.x); r[1] = (short)f2bf(a.y);
  r[2] = (short)f2bf(a.z); r[3] = (short)f2bf(a.w);
  r[4] = (short)f2bf(b.x); r[5] = (short)f2bf(b.y);
  r[6] = (short)f2bf(b.z); r[7] = (short)f2bf(b.w);
  return r;
}

// ---------------------------------------------------------------
// D1 front (1024t): msplitA | conv_w (WT -> global) | crel (8/block)
// all mutually independent.
// ---------------------------------------------------------------
__global__ __launch_bounds__(1024) void front(
    const float* __restrict__ W1, unsigned short* __restrict__ WT,
    const float* __restrict__ rel, const float* __restrict__ b1,
    const float* __restrict__ w2,
    unsigned short* __restrict__ Crelbf, float* __restrict__ pC, int n_rel,
    const int* __restrict__ dsts, unsigned int* __restrict__ cntg,
    unsigned char* __restrict__ rank8, int E, int words, int CB, int WB) {
  __shared__ __align__(16) unsigned int smem[MAXWORDS];  // 50176 B
  int b = blockIdx.x;
  int tid = threadIdx.x;
  if (b < CB) {
    // ---- msplitA: per-chunk LDS histogram + local rank (no global atomics)
    for (int w = tid; w < words; w += 1024) smem[w] = 0;
    __syncthreads();
    int base = b << CHUNK_SHIFT;
    int lim = E - base; if (lim > CHUNK_SZ) lim = CHUNK_SZ;
    for (int k = tid; k < lim; k += 1024) {
      int dn = dsts[base + k];
      unsigned int sh = 8u * (dn & 3);
      unsigned int old = atomicAdd(&smem[dn >> 2], 1u << sh);
      rank8[base + k] = (unsigned char)((old >> sh) & 0xFFu);
    }
    __syncthreads();
    unsigned int* dstp = cntg + (size_t)b * words;
    for (int w = tid; w < words; w += 1024) dstp[w] = smem[w];
  } else if (b < CB + WB) {
    // ---- conv_w: WT[n][k] = bf16(W1[(n>=128?128:0)+k][n&127]), 256x128
    int i = (b - CB) * 1024 + tid;   // exactly 32768 over 32 blocks
    int n = i >> 7, k = i & 127;
    int src_row = ((n >> 7) << 7) + k;
    WT[n * 128 + k] = f2bf(W1[src_row * 128 + (n & 127)]);
  } else {
    // ---- crel: 8 rel per block
    float* rs  = (float*)smem;          // [8][128]
    float* red = rs + 1024;             // [8][128]
    int h = tid >> 7, d = tid & 127;
    int r = (b - CB - WB) * 8 + h;
    bool valid = r < n_rel;
    rs[h * 128 + d] = valid ? rel[r * 128 + d] : 0.f;
    __syncthreads();
    float acc = b1[d];
    for (int k = 0; k < 128; ++k)
      acc = fmaf(rs[h * 128 + k], W1[(256 + k) * 128 + d], acc);
    if (valid) Crelbf[r * 128 + d] = f2bf(acc);
    red[h * 128 + d] = acc * w2[d];
    __syncthreads();
    for (int s = 64; s > 0; s >>= 1) {
      if (d < s) red[h * 128 + d] += red[h * 128 + d + s];
      __syncthreads();
    }
    if (d == 0 && valid) pC[r] = red[h * 128];
  }
}

// ---------------------------------------------------------------
// D2 mid (1024t): msplitB_scan1 (blocks < SB) | gemm (4 sub-tiles
// per block, global WT, zero LDS for gemm). Independent halves.
// ---------------------------------------------------------------
__global__ __launch_bounds__(1024, 1) void mid(
    const float* __restrict__ x, const unsigned short* __restrict__ WT,
    const float* __restrict__ w2,
    unsigned short* __restrict__ Abf, unsigned short* __restrict__ Bmbf,
    float* __restrict__ pA, float* __restrict__ pB, int M,
    const unsigned int* __restrict__ cntg, unsigned short* __restrict__ p16,
    int* __restrict__ deg, int* __restrict__ off, int* __restrict__ partial,
    int n, int words, int C, int SB) {
  __shared__ int sdata[1024];
  int b = blockIdx.x;
  int tid = threadIdx.x;

  if (b < SB) {
    // ---- msplitB + scan1: chunk-prefix p16, deg, block-local scan
    int t = tid;
    int i = b * 1024 + t;
    int run = 0;
    if (i < n) {
      int w = i >> 2, sh = 8 * (i & 3);
      for (int c = 0; c < C; ++c) {
        unsigned int cw = cntg[(size_t)c * words + w];
        p16[(size_t)c * n + i] = (unsigned short)run;
        run += (int)((cw >> sh) & 0xFFu);
      }
      deg[i] = run;
    }
    int v = (i < n) ? run : 0;
    sdata[t] = v;
    __syncthreads();
    for (int s = 1; s < 1024; s <<= 1) {
      int add = (t >= s) ? sdata[t - s] : 0;
      __syncthreads();
      sdata[t] += add;
      __syncthreads();
    }
    if (i < n) off[i] = sdata[t] - v;   // block-local exclusive
    if (t == 1023) partial[b] = sdata[1023];
    return;
  }

  // ---- gemm: 4 independent 64-row sub-tiles (256 threads each)
  int sub = tid >> 8;
  int t   = tid & 255;
  int m0  = ((b - SB) * 4 + sub) * 64;
  if (m0 >= M) return;

  int wave = t >> 6, lane = t & 63;
  int wm = wave >> 1, wn = wave & 1;
  int l15 = lane & 15, l4 = lane >> 4;

  f32x4 acc[2][8];
  #pragma unroll
  for (int mi = 0; mi < 2; ++mi)
    #pragma unroll
    for (int ni = 0; ni < 8; ++ni) acc[mi][ni] = (f32x4){0.f, 0.f, 0.f, 0.f};

  int arow0 = m0 + wm * 32 + l15;
  int arow1 = arow0 + 16;
  int ar0 = arow0 < M ? arow0 : M - 1;
  int ar1 = arow1 < M ? arow1 : M - 1;
  const float* xbase0 = x + (size_t)ar0 * 128 + l4 * 8;
  const float* xbase1 = x + (size_t)ar1 * 128 + l4 * 8;
  const unsigned short* bbase = WT + (size_t)(wn * 128 + l15) * 128 + l4 * 8;

  #pragma unroll
  for (int ks = 0; ks < 4; ++ks) {
    float4 a0lo = *(const float4*)(xbase0 + ks * 32);
    float4 a0hi = *(const float4*)(xbase0 + ks * 32 + 4);
    float4 a1lo = *(const float4*)(xbase1 + ks * 32);
    float4 a1hi = *(const float4*)(xbase1 + ks * 32 + 4);
    bf16x8 af0 = pack8(a0lo, a0hi);
    bf16x8 af1 = pack8(a1lo, a1hi);
    #pragma unroll
    for (int ni = 0; ni < 8; ++ni) {
      bf16x8 bf = *(const bf16x8*)(bbase + ni * 16 * 128 + ks * 32);
      acc[0][ni] = __builtin_amdgcn_mfma_f32_16x16x32_bf16(af0, bf, acc[0][ni], 0, 0, 0);
      acc[1][ni] = __builtin_amdgcn_mfma_f32_16x16x32_bf16(af1, bf, acc[1][ni], 0, 0, 0);
    }
  }

  // C/D layout: col = ni*16 + l15, row = m0 + wm*32 + mi*16 + l4*4 + r
  unsigned short* dstp = (wn == 0) ? Abf : Bmbf;
  #pragma unroll
  for (int mi = 0; mi < 2; ++mi) {
    #pragma unroll
    for (int ni = 0; ni < 8; ++ni) {
      int coll = ni * 16 + l15;
      #pragma unroll
      for (int r = 0; r < 4; ++r) {
        int row = m0 + wm * 32 + mi * 16 + l4 * 4 + r;
        if (row < M) dstp[(size_t)row * 128 + coll] = f2bf(acc[mi][ni][r]);
      }
    }
  }

  float w2c[8];
  #pragma unroll
  for (int ni = 0; ni < 8; ++ni) w2c[ni] = w2[ni * 16 + l15];
  float* pdst = (wn == 0) ? pA : pB;
  #pragma unroll
  for (int mi = 0; mi < 2; ++mi) {
    #pragma unroll
    for (int r = 0; r < 4; ++r) {
      float v = 0.f;
      #pragma unroll
      for (int ni = 0; ni < 8; ++ni) v = fmaf(acc[mi][ni][r], w2c[ni], v);
      v += __shfl_xor(v, 1, 64);
      v += __shfl_xor(v, 2, 64);
      v += __shfl_xor(v, 4, 64);
      v += __shfl_xor(v, 8, 64);
      if (l15 == 0) {
        int row = m0 + wm * 32 + mi * 16 + l4 * 4 + r;
        if (row < M) pdst[row] = v;
      }
    }
  }
}

// ---------------------------------------------------------------
// fill CSR slots, atomic-free, inline carry prefix:
// slot = off[dst] + carry[dst>>10] + p16[chunk][dst] + rank8[e]
// ---------------------------------------------------------------
__global__ __launch_bounds__(256) void fill_perm(
    const int* __restrict__ srcs, const int* __restrict__ dsts,
    const int* __restrict__ types, const unsigned char* __restrict__ rank8,
    const int* __restrict__ off, const int* __restrict__ partial, int nb,
    const unsigned short* __restrict__ p16,
    unsigned int* __restrict__ stperm, int E, int n) {
  __shared__ int carryLUT[64];
  int tid = threadIdx.x;
  if (tid < 64) {
    int v = (tid < nb) ? partial[tid] : 0;
    int inc = v;
    #pragma unroll
    for (int s = 1; s < 64; s <<= 1) {
      int u = __shfl_up(inc, s, 64);
      if (tid >= s) inc += u;
    }
    carryLUT[tid] = inc - v;   // exclusive prefix
  }
  __syncthreads();
  int i = blockIdx.x * 256 + tid;
  if (i < E) {
    int dn = dsts[i];
    int c = i >> CHUNK_SHIFT;
    int p = off[dn] + carryLUT[dn >> 10] + (int)p16[(size_t)c * n + dn] + (int)rank8[i];
    stperm[p] = (unsigned int)srcs[i] | ((unsigned int)types[i] << 16);
  }
}

// ---------------------------------------------------------------
// Aggregate: 2 nodes per wave (32 lanes x 4 cols, uint2 gathers),
// inline carry prefix, shift-free softmax.
// out[n] = lrelu( sum_e alpha_e (A[s]+Crel[t]) + B[n] )
// ---------------------------------------------------------------
__global__ __launch_bounds__(256) void aggregate(
    const int* __restrict__ off, const int* __restrict__ deg,
    const int* __restrict__ partial, int nb,
    const unsigned int* __restrict__ stperm,
    const float* __restrict__ pA, const float* __restrict__ pB,
    const float* __restrict__ pCg,
    const unsigned short* __restrict__ Abf,
    const unsigned short* __restrict__ Bmbf,
    const unsigned short* __restrict__ Crelbf,
    float* __restrict__ out, int n_nodes, int n_rel) {
  __shared__ float pCs[256];
  __shared__ int carryLUT[64];
  int tid = threadIdx.x;
  if (tid < 64) {
    int v = (tid < nb) ? partial[tid] : 0;
    int inc = v;
    #pragma unroll
    for (int s = 1; s < 64; s <<= 1) {
      int u = __shfl_up(inc, s, 64);
      if (tid >= s) inc += u;
    }
    carryLUT[tid] = inc - v;
  }
  for (int r = tid; r < n_rel; r += 256) pCs[r] = pCg[r];
  __syncthreads();

  int n = blockIdx.x * 8 + (tid >> 5);   // 8 nodes per block
  if (n >= n_nodes) return;
  int lane = tid & 31;
  int c4 = lane * 4;                      // 4 bf16 cols per lane
  int start = off[n] + carryLUT[n >> 10];
  int dcnt = deg[n];
  size_t obase = (size_t)n * 128 + c4;
  if (dcnt == 0) {
    *(float4*)(out + obase) = (float4){0.f, 0.f, 0.f, 0.f};
    return;
  }
  float pBn = pB[n];
  float acc0 = 0.f, acc1 = 0.f, acc2 = 0.f, acc3 = 0.f, S = 0.f;
  int i = 0;
  for (; i + 4 <= dcnt; i += 4) {
    unsigned int st[4];
    #pragma unroll
    for (int j = 0; j < 4; ++j) st[j] = stperm[start + i + j];
    uint2 av[4], cv[4];
    float pa[4];
    #pragma unroll
    for (int j = 0; j < 4; ++j) {
      unsigned int s = st[j] & 0xFFFFu, t = st[j] >> 16;
      av[j] = *(const uint2*)(Abf + ((size_t)s << 7) + c4);
      cv[j] = *(const uint2*)(Crelbf + (t << 7) + c4);
      pa[j] = pA[s];
    }
    #pragma unroll
    for (int j = 0; j < 4; ++j) {
      float b = pa[j] + pBn + pCs[st[j] >> 16];
      b = b > 0.f ? b : SLOPE * b;
      float ex = __expf(b);
      S += ex;
      acc0 = fmaf(ex, bflo(av[j].x) + bflo(cv[j].x), acc0);
      acc1 = fmaf(ex, bfhi(av[j].x) + bfhi(cv[j].x), acc1);
      acc2 = fmaf(ex, bflo(av[j].y) + bflo(cv[j].y), acc2);
      acc3 = fmaf(ex, bfhi(av[j].y) + bfhi(cv[j].y), acc3);
    }
  }
  for (; i < dcnt; ++i) {
    unsigned int st = stperm[start + i];
    unsigned int s = st & 0xFFFFu, t = st >> 16;
    uint2 av = *(const uint2*)(Abf + ((size_t)s << 7) + c4);
    uint2 cv = *(const uint2*)(Crelbf + (t << 7) + c4);
    float b = pA[s] + pBn + pCs[t];
    b = b > 0.f ? b : SLOPE * b;
    float ex = __expf(b);
    S += ex;
    acc0 = fmaf(ex, bflo(av.x) + bflo(cv.x), acc0);
    acc1 = fmaf(ex, bfhi(av.x) + bfhi(cv.x), acc1);
    acc2 = fmaf(ex, bflo(av.y) + bflo(cv.y), acc2);
    acc3 = fmaf(ex, bfhi(av.y) + bfhi(cv.y), acc3);
  }
  float inv = 1.f / S;
  uint2 bm = *(const uint2*)(Bmbf + obase);
  float o0 = acc0 * inv + bflo(bm.x);
  float o1 = acc1 * inv + bfhi(bm.x);
  float o2 = acc2 * inv + bflo(bm.y);
  float o3 = acc3 * inv + bfhi(bm.y);
  o0 = o0 > 0.f ? o0 : SLOPE * o0;
  o1 = o1 > 0.f ? o1 : SLOPE * o1;
  o2 = o2 > 0.f ? o2 : SLOPE * o2;
  o3 = o3 > 0.f ? o3 : SLOPE * o3;
  *(float4*)(out + obase) = (float4){o0, o1, o2, o3};
}

extern "C" void kernel_launch(void* const* d_in, const int* in_sizes, int n_in,
                              void* d_out, int out_size, void* d_ws, size_t ws_size,
                              hipStream_t stream) {
  const float* x    = (const float*)d_in[0];
  const float* rel  = (const float*)d_in[1];
  const float* W1   = (const float*)d_in[2];
  const float* b1   = (const float*)d_in[3];
  const float* w2   = (const float*)d_in[4];
  const int* edge_index = (const int*)d_in[5];
  const int* edge_type  = (const int*)d_in[6];

  int n_nodes = in_sizes[0] / 128;
  int n_rel   = in_sizes[1] / 128;
  int E       = in_sizes[6];
  const int* srcs = edge_index;
  const int* dsts = edge_index + E;
  float* out = (float*)d_out;

  int words = (n_nodes + 3) >> 2;
  int C     = (E + CHUNK_SZ - 1) >> CHUNK_SHIFT;

  auto align256 = [](size_t v) { return (v + 255) & ~(size_t)255; };
  char* ws = (char*)d_ws;
  unsigned short* WT     = (unsigned short*)ws; ws += align256(256 * 128 * 2);
  unsigned short* Abf    = (unsigned short*)ws; ws += align256((size_t)n_nodes * 128 * 2);
  unsigned short* Bmbf   = (unsigned short*)ws; ws += align256((size_t)n_nodes * 128 * 2);
  unsigned short* Crelbf = (unsigned short*)ws; ws += align256((size_t)n_rel * 128 * 2);
  float* pA    = (float*)ws; ws += align256((size_t)n_nodes * 4);
  float* pB    = (float*)ws; ws += align256((size_t)n_nodes * 4);
  float* pC    = (float*)ws; ws += align256((size_t)n_rel * 4);
  int* deg     = (int*)ws;   ws += align256((size_t)n_nodes * 4);
  int* off     = (int*)ws;   ws += align256((size_t)n_nodes * 4);
  int* partial = (int*)ws;   ws += align256(1024 * 4);
  unsigned int* cntg = (unsigned int*)ws;    ws += align256((size_t)C * words * 4);
  unsigned short* p16 = (unsigned short*)ws; ws += align256((size_t)C * n_nodes * 2);
  unsigned char* rank8 = (unsigned char*)ws; ws += align256((size_t)E);
  unsigned int* stperm = (unsigned int*)ws;  ws += align256((size_t)E * 4);

  // D1: msplitA | conv_w | crel
  int CB = C;                          // 62 msplitA blocks first
  int WB = 32;                         // conv_w: 32768 elems / 1024
  int RB = (n_rel + 7) / 8;            // crel blocks
  front<<<CB + WB + RB, 1024, 0, stream>>>(
      W1, WT, rel, b1, w2, Crelbf, pC, n_rel,
      dsts, cntg, rank8, E, words, CB, WB);

  // D2: msplitB_scan1 | gemm (4 sub-tiles per block)
  int nb = (n_nodes + 1023) / 1024;    // must be <= 64
  int gB = (n_nodes + 63) / 64;
  int gB4 = (gB + 3) / 4;
  mid<<<nb + gB4, 1024, 0, stream>>>(
      x, WT, w2, Abf, Bmbf, pA, pB, n_nodes,
      cntg, p16, deg, off, partial, n_nodes, words, C, nb);

  // D3: fill CSR
  fill_perm<<<(E + 255) / 256, 256, 0, stream>>>(
      srcs, dsts, edge_type, rank8, off, partial, nb, p16, stperm, E, n_nodes);

  // D4: aggregate
  aggregate<<<(n_nodes + 7) / 8, 256, 0, stream>>>(
      off, deg, partial, nb, stperm, pA, pB, pC, Abf, Bmbf, Crelbf,
      out, n_nodes, n_rel);
}

// Round 13
// 87.625 us; speedup vs baseline: 1.3858x; 1.0373x over previous
//
#include <hip/hip_runtime.h>
#include <math.h>

#define SLOPE 0.01f
#define CHUNK_SHIFT 13
#define CHUNK_SZ (1 << CHUNK_SHIFT)
#define MAXWORDS 12544   // supports n_nodes <= 50176 (problem: 50000)

using bf16x8 = __attribute__((ext_vector_type(8))) short;
using f32x4  = __attribute__((ext_vector_type(4))) float;

__device__ __forceinline__ unsigned short f2bf(float f) {
  unsigned int u = __float_as_uint(f);
  unsigned int r = 0x7FFFu + ((u >> 16) & 1u);
  return (unsigned short)((u + r) >> 16);
}
__device__ __forceinline__ float bflo(unsigned int v) {
  return __uint_as_float(v << 16);
}
__device__ __forceinline__ float bfhi(unsigned int v) {
  return __uint_as_float(v & 0xFFFF0000u);
}
__device__ __forceinline__ bf16x8 pack8(float4 a, float4 b) {
  bf16x8 r;
  r[0] = (short)f2bf(a.x); r[1] = (short)f2bf(a.y);
  r[2] = (short)f2bf(a.z); r[3] = (short)f2bf(a.w);
  r[4] = (short)f2bf(b.x); r[5] = (short)f2bf(b.y);
  r[6] = (short)f2bf(b.z); r[7] = (short)f2bf(b.w);
  return r;
}

// ---------------------------------------------------------------
// D1 front (1024t): msplitA | conv_w (WT -> global) | crel (8/block)
// all mutually independent.
// ---------------------------------------------------------------
__global__ __launch_bounds__(1024) void front(
    const float* __restrict__ W1, unsigned short* __restrict__ WT,
    const float* __restrict__ rel, const float* __restrict__ b1,
    const float* __restrict__ w2,
    unsigned short* __restrict__ Crelbf, float* __restrict__ pC, int n_rel,
    const int* __restrict__ dsts, unsigned int* __restrict__ cntg,
    unsigned char* __restrict__ rank8, int E, int words, int CB, int WB) {
  __shared__ __align__(16) unsigned int smem[MAXWORDS];  // 50176 B
  int b = blockIdx.x;
  int tid = threadIdx.x;
  if (b < CB) {
    // ---- msplitA: per-chunk LDS histogram + local rank (no global atomics)
    for (int w = tid; w < words; w += 1024) smem[w] = 0;
    __syncthreads();
    int base = b << CHUNK_SHIFT;
    int lim = E - base; if (lim > CHUNK_SZ) lim = CHUNK_SZ;
    for (int k = tid; k < lim; k += 1024) {
      int dn = dsts[base + k];
      unsigned int sh = 8u * (dn & 3);
      unsigned int old = atomicAdd(&smem[dn >> 2], 1u << sh);
      rank8[base + k] = (unsigned char)((old >> sh) & 0xFFu);
    }
    __syncthreads();
    unsigned int* dstp = cntg + (size_t)b * words;
    for (int w = tid; w < words; w += 1024) dstp[w] = smem[w];
  } else if (b < CB + WB) {
    // ---- conv_w: WT[n][k] = bf16(W1[(n>=128?128:0)+k][n&127]), 256x128
    int i = (b - CB) * 1024 + tid;   // exactly 32768 over 32 blocks
    int n = i >> 7, k = i & 127;
    int src_row = ((n >> 7) << 7) + k;
    WT[n * 128 + k] = f2bf(W1[src_row * 128 + (n & 127)]);
  } else {
    // ---- crel: 8 rel per block
    float* rs  = (float*)smem;          // [8][128]
    float* red = rs + 1024;             // [8][128]
    int h = tid >> 7, d = tid & 127;
    int r = (b - CB - WB) * 8 + h;
    bool valid = r < n_rel;
    rs[h * 128 + d] = valid ? rel[r * 128 + d] : 0.f;
    __syncthreads();
    float acc = b1[d];
    for (int k = 0; k < 128; ++k)
      acc = fmaf(rs[h * 128 + k], W1[(256 + k) * 128 + d], acc);
    if (valid) Crelbf[r * 128 + d] = f2bf(acc);
    red[h * 128 + d] = acc * w2[d];
    __syncthreads();
    for (int s = 64; s > 0; s >>= 1) {
      if (d < s) red[h * 128 + d] += red[h * 128 + d + s];
      __syncthreads();
    }
    if (d == 0 && valid) pC[r] = red[h * 128];
  }
}

// ---------------------------------------------------------------
// D2 mid (1024t): msplitB_scan1 (blocks < SB) | gemm (4 sub-tiles
// per block, global WT, zero LDS for gemm). Independent halves.
// ---------------------------------------------------------------
__global__ __launch_bounds__(1024, 1) void mid(
    const float* __restrict__ x, const unsigned short* __restrict__ WT,
    const float* __restrict__ w2,
    unsigned short* __restrict__ Abf, unsigned short* __restrict__ Bmbf,
    float* __restrict__ pA, float* __restrict__ pB, int M,
    const unsigned int* __restrict__ cntg, unsigned short* __restrict__ p16,
    int* __restrict__ deg, int* __restrict__ off, int* __restrict__ partial,
    int n, int words, int C, int SB) {
  __shared__ int sdata[1024];
  int b = blockIdx.x;
  int tid = threadIdx.x;

  if (b < SB) {
    // ---- msplitB + scan1: chunk-prefix p16, deg, block-local scan
    int t = tid;
    int i = b * 1024 + t;
    int run = 0;
    if (i < n) {
      int w = i >> 2, sh = 8 * (i & 3);
      for (int c = 0; c < C; ++c) {
        unsigned int cw = cntg[(size_t)c * words + w];
        p16[(size_t)c * n + i] = (unsigned short)run;
        run += (int)((cw >> sh) & 0xFFu);
      }
      deg[i] = run;
    }
    int v = (i < n) ? run : 0;
    sdata[t] = v;
    __syncthreads();
    for (int s = 1; s < 1024; s <<= 1) {
      int add = (t >= s) ? sdata[t - s] : 0;
      __syncthreads();
      sdata[t] += add;
      __syncthreads();
    }
    if (i < n) off[i] = sdata[t] - v;   // block-local exclusive
    if (t == 1023) partial[b] = sdata[1023];
    return;
  }

  // ---- gemm: 4 independent 64-row sub-tiles (256 threads each)
  int sub = tid >> 8;
  int t   = tid & 255;
  int m0  = ((b - SB) * 4 + sub) * 64;
  if (m0 >= M) return;

  int wave = t >> 6, lane = t & 63;
  int wm = wave >> 1, wn = wave & 1;
  int l15 = lane & 15, l4 = lane >> 4;

  f32x4 acc[2][8];
  #pragma unroll
  for (int mi = 0; mi < 2; ++mi)
    #pragma unroll
    for (int ni = 0; ni < 8; ++ni) acc[mi][ni] = (f32x4){0.f, 0.f, 0.f, 0.f};

  int arow0 = m0 + wm * 32 + l15;
  int arow1 = arow0 + 16;
  int ar0 = arow0 < M ? arow0 : M - 1;
  int ar1 = arow1 < M ? arow1 : M - 1;
  const float* xbase0 = x + (size_t)ar0 * 128 + l4 * 8;
  const float* xbase1 = x + (size_t)ar1 * 128 + l4 * 8;
  const unsigned short* bbase = WT + (size_t)(wn * 128 + l15) * 128 + l4 * 8;

  #pragma unroll
  for (int ks = 0; ks < 4; ++ks) {
    float4 a0lo = *(const float4*)(xbase0 + ks * 32);
    float4 a0hi = *(const float4*)(xbase0 + ks * 32 + 4);
    float4 a1lo = *(const float4*)(xbase1 + ks * 32);
    float4 a1hi = *(const float4*)(xbase1 + ks * 32 + 4);
    bf16x8 af0 = pack8(a0lo, a0hi);
    bf16x8 af1 = pack8(a1lo, a1hi);
    #pragma unroll
    for (int ni = 0; ni < 8; ++ni) {
      bf16x8 bf = *(const bf16x8*)(bbase + ni * 16 * 128 + ks * 32);
      acc[0][ni] = __builtin_amdgcn_mfma_f32_16x16x32_bf16(af0, bf, acc[0][ni], 0, 0, 0);
      acc[1][ni] = __builtin_amdgcn_mfma_f32_16x16x32_bf16(af1, bf, acc[1][ni], 0, 0, 0);
    }
  }

  // C/D layout: col = ni*16 + l15, row = m0 + wm*32 + mi*16 + l4*4 + r
  unsigned short* dstp = (wn == 0) ? Abf : Bmbf;
  #pragma unroll
  for (int mi = 0; mi < 2; ++mi) {
    #pragma unroll
    for (int ni = 0; ni < 8; ++ni) {
      int coll = ni * 16 + l15;
      #pragma unroll
      for (int r = 0; r < 4; ++r) {
        int row = m0 + wm * 32 + mi * 16 + l4 * 4 + r;
        if (row < M) dstp[(size_t)row * 128 + coll] = f2bf(acc[mi][ni][r]);
      }
    }
  }

  float w2c[8];
  #pragma unroll
  for (int ni = 0; ni < 8; ++ni) w2c[ni] = w2[ni * 16 + l15];
  float* pdst = (wn == 0) ? pA : pB;
  #pragma unroll
  for (int mi = 0; mi < 2; ++mi) {
    #pragma unroll
    for (int r = 0; r < 4; ++r) {
      float v = 0.f;
      #pragma unroll
      for (int ni = 0; ni < 8; ++ni) v = fmaf(acc[mi][ni][r], w2c[ni], v);
      v += __shfl_xor(v, 1, 64);
      v += __shfl_xor(v, 2, 64);
      v += __shfl_xor(v, 4, 64);
      v += __shfl_xor(v, 8, 64);
      if (l15 == 0) {
        int row = m0 + wm * 32 + mi * 16 + l4 * 4 + r;
        if (row < M) pdst[row] = v;
      }
    }
  }
}

// ---------------------------------------------------------------
// fill CSR slots, atomic-free, inline carry prefix:
// slot = off[dst] + carry[dst>>10] + p16[chunk][dst] + rank8[e]
// ---------------------------------------------------------------
__global__ __launch_bounds__(1024) void fill_perm(
    const int* __restrict__ srcs, const int* __restrict__ dsts,
    const int* __restrict__ types, const unsigned char* __restrict__ rank8,
    const int* __restrict__ off, const int* __restrict__ partial, int nb,
    const unsigned short* __restrict__ p16,
    unsigned int* __restrict__ stperm, int E, int n) {
  __shared__ int carryLUT[64];
  int tid = threadIdx.x;
  if (tid < 64) {
    int v = (tid < nb) ? partial[tid] : 0;
    int inc = v;
    #pragma unroll
    for (int s = 1; s < 64; s <<= 1) {
      int u = __shfl_up(inc, s, 64);
      if (tid >= s) inc += u;
    }
    carryLUT[tid] = inc - v;   // exclusive prefix
  }
  __syncthreads();
  int i = blockIdx.x * 1024 + tid;
  if (i < E) {
    int dn = dsts[i];
    int c = i >> CHUNK_SHIFT;
    int p = off[dn] + carryLUT[dn >> 10] + (int)p16[(size_t)c * n + dn] + (int)rank8[i];
    stperm[p] = (unsigned int)srcs[i] | ((unsigned int)types[i] << 16);
  }
}

// ---------------------------------------------------------------
// Aggregate: 4 nodes per wave (16 lanes x 8 cols, uint4 gathers)
// -> 2x independent edge streams vs r12. Inline carry prefix.
// Shift-free softmax. out[n] = lrelu( sum_e alpha_e(A[s]+Crel[t]) + B[n] )
// ---------------------------------------------------------------
__global__ __launch_bounds__(256) void aggregate(
    const int* __restrict__ off, const int* __restrict__ deg,
    const int* __restrict__ partial, int nb,
    const unsigned int* __restrict__ stperm,
    const float* __restrict__ pA, const float* __restrict__ pB,
    const float* __restrict__ pCg,
    const unsigned short* __restrict__ Abf,
    const unsigned short* __restrict__ Bmbf,
    const unsigned short* __restrict__ Crelbf,
    float* __restrict__ out, int n_nodes, int n_rel) {
  __shared__ float pCs[256];
  __shared__ int carryLUT[64];
  int tid = threadIdx.x;
  if (tid < 64) {
    int v = (tid < nb) ? partial[tid] : 0;
    int inc = v;
    #pragma unroll
    for (int s = 1; s < 64; s <<= 1) {
      int u = __shfl_up(inc, s, 64);
      if (tid >= s) inc += u;
    }
    carryLUT[tid] = inc - v;
  }
  for (int r = tid; r < n_rel; r += 256) pCs[r] = pCg[r];
  __syncthreads();

  int n = blockIdx.x * 16 + (tid >> 4);   // 16 nodes per block
  if (n >= n_nodes) return;
  int lane = tid & 15;
  int c8 = lane * 8;                       // 8 bf16 cols per lane
  int start = off[n] + carryLUT[n >> 10];
  int dcnt = deg[n];
  size_t obase = (size_t)n * 128 + c8;
  if (dcnt == 0) {
    *(float4*)(out + obase)     = (float4){0.f, 0.f, 0.f, 0.f};
    *(float4*)(out + obase + 4) = (float4){0.f, 0.f, 0.f, 0.f};
    return;
  }
  float pBn = pB[n];
  float a0 = 0.f, a1 = 0.f, a2 = 0.f, a3 = 0.f;
  float a4 = 0.f, a5 = 0.f, a6 = 0.f, a7 = 0.f, S = 0.f;
  int i = 0;
  for (; i + 4 <= dcnt; i += 4) {
    unsigned int st[4];
    #pragma unroll
    for (int j = 0; j < 4; ++j) st[j] = stperm[start + i + j];
    uint4 av[4], cv[4];
    float pa[4];
    #pragma unroll
    for (int j = 0; j < 4; ++j) {
      unsigned int s = st[j] & 0xFFFFu, t = st[j] >> 16;
      av[j] = *(const uint4*)(Abf + ((size_t)s << 7) + c8);
      cv[j] = *(const uint4*)(Crelbf + (t << 7) + c8);
      pa[j] = pA[s];
    }
    #pragma unroll
    for (int j = 0; j < 4; ++j) {
      float b = pa[j] + pBn + pCs[st[j] >> 16];
      b = b > 0.f ? b : SLOPE * b;
      float ex = __expf(b);
      S += ex;
      a0 = fmaf(ex, bflo(av[j].x) + bflo(cv[j].x), a0);
      a1 = fmaf(ex, bfhi(av[j].x) + bfhi(cv[j].x), a1);
      a2 = fmaf(ex, bflo(av[j].y) + bflo(cv[j].y), a2);
      a3 = fmaf(ex, bfhi(av[j].y) + bfhi(cv[j].y), a3);
      a4 = fmaf(ex, bflo(av[j].z) + bflo(cv[j].z), a4);
      a5 = fmaf(ex, bfhi(av[j].z) + bfhi(cv[j].z), a5);
      a6 = fmaf(ex, bflo(av[j].w) + bflo(cv[j].w), a6);
      a7 = fmaf(ex, bfhi(av[j].w) + bfhi(cv[j].w), a7);
    }
  }
  for (; i < dcnt; ++i) {
    unsigned int st = stperm[start + i];
    unsigned int s = st & 0xFFFFu, t = st >> 16;
    uint4 av = *(const uint4*)(Abf + ((size_t)s << 7) + c8);
    uint4 cv = *(const uint4*)(Crelbf + (t << 7) + c8);
    float b = pA[s] + pBn + pCs[t];
    b = b > 0.f ? b : SLOPE * b;
    float ex = __expf(b);
    S += ex;
    a0 = fmaf(ex, bflo(av.x) + bflo(cv.x), a0);
    a1 = fmaf(ex, bfhi(av.x) + bfhi(cv.x), a1);
    a2 = fmaf(ex, bflo(av.y) + bflo(cv.y), a2);
    a3 = fmaf(ex, bfhi(av.y) + bfhi(cv.y), a3);
    a4 = fmaf(ex, bflo(av.z) + bflo(cv.z), a4);
    a5 = fmaf(ex, bfhi(av.z) + bfhi(cv.z), a5);
    a6 = fmaf(ex, bflo(av.w) + bflo(cv.w), a6);
    a7 = fmaf(ex, bfhi(av.w) + bfhi(cv.w), a7);
  }
  float inv = 1.f / S;
  uint4 bm = *(const uint4*)(Bmbf + obase);
  float o0 = a0 * inv + bflo(bm.x);
  float o1 = a1 * inv + bfhi(bm.x);
  float o2 = a2 * inv + bflo(bm.y);
  float o3 = a3 * inv + bfhi(bm.y);
  float o4 = a4 * inv + bflo(bm.z);
  float o5 = a5 * inv + bfhi(bm.z);
  float o6 = a6 * inv + bflo(bm.w);
  float o7 = a7 * inv + bfhi(bm.w);
  o0 = o0 > 0.f ? o0 : SLOPE * o0;
  o1 = o1 > 0.f ? o1 : SLOPE * o1;
  o2 = o2 > 0.f ? o2 : SLOPE * o2;
  o3 = o3 > 0.f ? o3 : SLOPE * o3;
  o4 = o4 > 0.f ? o4 : SLOPE * o4;
  o5 = o5 > 0.f ? o5 : SLOPE * o5;
  o6 = o6 > 0.f ? o6 : SLOPE * o6;
  o7 = o7 > 0.f ? o7 : SLOPE * o7;
  *(float4*)(out + obase)     = (float4){o0, o1, o2, o3};
  *(float4*)(out + obase + 4) = (float4){o4, o5, o6, o7};
}

extern "C" void kernel_launch(void* const* d_in, const int* in_sizes, int n_in,
                              void* d_out, int out_size, void* d_ws, size_t ws_size,
                              hipStream_t stream) {
  const float* x    = (const float*)d_in[0];
  const float* rel  = (const float*)d_in[1];
  const float* W1   = (const float*)d_in[2];
  const float* b1   = (const float*)d_in[3];
  const float* w2   = (const float*)d_in[4];
  const int* edge_index = (const int*)d_in[5];
  const int* edge_type  = (const int*)d_in[6];

  int n_nodes = in_sizes[0] / 128;
  int n_rel   = in_sizes[1] / 128;
  int E       = in_sizes[6];
  const int* srcs = edge_index;
  const int* dsts = edge_index + E;
  float* out = (float*)d_out;

  int words = (n_nodes + 3) >> 2;
  int C     = (E + CHUNK_SZ - 1) >> CHUNK_SHIFT;

  auto align256 = [](size_t v) { return (v + 255) & ~(size_t)255; };
  char* ws = (char*)d_ws;
  unsigned short* WT     = (unsigned short*)ws; ws += align256(256 * 128 * 2);
  unsigned short* Abf    = (unsigned short*)ws; ws += align256((size_t)n_nodes * 128 * 2);
  unsigned short* Bmbf   = (unsigned short*)ws; ws += align256((size_t)n_nodes * 128 * 2);
  unsigned short* Crelbf = (unsigned short*)ws; ws += align256((size_t)n_rel * 128 * 2);
  float* pA    = (float*)ws; ws += align256((size_t)n_nodes * 4);
  float* pB    = (float*)ws; ws += align256((size_t)n_nodes * 4);
  float* pC    = (float*)ws; ws += align256((size_t)n_rel * 4);
  int* deg     = (int*)ws;   ws += align256((size_t)n_nodes * 4);
  int* off     = (int*)ws;   ws += align256((size_t)n_nodes * 4);
  int* partial = (int*)ws;   ws += align256(1024 * 4);
  unsigned int* cntg = (unsigned int*)ws;    ws += align256((size_t)C * words * 4);
  unsigned short* p16 = (unsigned short*)ws; ws += align256((size_t)C * n_nodes * 2);
  unsigned char* rank8 = (unsigned char*)ws; ws += align256((size_t)E);
  unsigned int* stperm = (unsigned int*)ws;  ws += align256((size_t)E * 4);

  // D1: msplitA | conv_w | crel
  int CB = C;                          // 62 msplitA blocks first
  int WB = 32;                         // conv_w: 32768 elems / 1024
  int RB = (n_rel + 7) / 8;            // crel blocks
  front<<<CB + WB + RB, 1024, 0, stream>>>(
      W1, WT, rel, b1, w2, Crelbf, pC, n_rel,
      dsts, cntg, rank8, E, words, CB, WB);

  // D2: msplitB_scan1 | gemm (4 sub-tiles per block)
  int nb = (n_nodes + 1023) / 1024;    // must be <= 64
  int gB = (n_nodes + 63) / 64;
  int gB4 = (gB + 3) / 4;
  mid<<<nb + gB4, 1024, 0, stream>>>(
      x, WT, w2, Abf, Bmbf, pA, pB, n_nodes,
      cntg, p16, deg, off, partial, n_nodes, words, C, nb);

  // D3: fill CSR
  fill_perm<<<(E + 1023) / 1024, 1024, 0, stream>>>(
      srcs, dsts, edge_type, rank8, off, partial, nb, p16, stperm, E, n_nodes);

  // D4: aggregate
  aggregate<<<(n_nodes + 15) / 16, 256, 0, stream>>>(
      off, deg, partial, nb, stperm, pA, pB, pC, Abf, Bmbf, Crelbf,
      out, n_nodes, n_rel);
}

// Round 14
// 78.570 us; speedup vs baseline: 1.5455x; 1.1152x over previous
//
#include <hip/hip_runtime.h>
#include <math.h>

#define SLOPE 0.01f
#define CHUNK_SHIFT 13
#define CHUNK_SZ (1 << CHUNK_SHIFT)
#define MAXWORDS 12544   // supports n_nodes <= 50176 (problem: 50000)

using bf16x8 = __attribute__((ext_vector_type(8))) short;
using f32x4  = __attribute__((ext_vector_type(4))) float;

__device__ __forceinline__ unsigned short f2bf(float f) {
  unsigned int u = __float_as_uint(f);
  unsigned int r = 0x7FFFu + ((u >> 16) & 1u);
  return (unsigned short)((u + r) >> 16);
}
__device__ __forceinline__ float bflo(unsigned int v) {
  return __uint_as_float(v << 16);
}
__device__ __forceinline__ float bfhi(unsigned int v) {
  return __uint_as_float(v & 0xFFFF0000u);
}
__device__ __forceinline__ bf16x8 pack8(float4 a, float4 b) {
  bf16x8 r;
  r[0] = (short)f2bf(a.x); r[1] = (short)f2bf(a.y);
  r[2] = (short)f2bf(a.z); r[3] = (short)f2bf(a.w);
  r[4] = (short)f2bf(b.x); r[5] = (short)f2bf(b.y);
  r[6] = (short)f2bf(b.z); r[7] = (short)f2bf(b.w);
  return r;
}

// ---------------------------------------------------------------
// D1 front (1024t): msplitA | conv_w (WT -> global) | crel (8/block)
// all mutually independent.
// ---------------------------------------------------------------
__global__ __launch_bounds__(1024) void front(
    const float* __restrict__ W1, unsigned short* __restrict__ WT,
    const float* __restrict__ rel, const float* __restrict__ b1,
    const float* __restrict__ w2,
    unsigned short* __restrict__ Crelbf, float* __restrict__ pC, int n_rel,
    const int* __restrict__ dsts, unsigned int* __restrict__ cntg,
    unsigned char* __restrict__ rank8, int E, int words, int CB, int WB) {
  __shared__ __align__(16) unsigned int smem[MAXWORDS];  // 50176 B
  int b = blockIdx.x;
  int tid = threadIdx.x;
  if (b < CB) {
    // ---- msplitA: per-chunk LDS histogram + local rank (no global atomics)
    for (int w = tid; w < words; w += 1024) smem[w] = 0;
    __syncthreads();
    int base = b << CHUNK_SHIFT;
    int lim = E - base; if (lim > CHUNK_SZ) lim = CHUNK_SZ;
    for (int k = tid; k < lim; k += 1024) {
      int dn = dsts[base + k];
      unsigned int sh = 8u * (dn & 3);
      unsigned int old = atomicAdd(&smem[dn >> 2], 1u << sh);
      rank8[base + k] = (unsigned char)((old >> sh) & 0xFFu);
    }
    __syncthreads();
    unsigned int* dstp = cntg + (size_t)b * words;
    for (int w = tid; w < words; w += 1024) dstp[w] = smem[w];
  } else if (b < CB + WB) {
    // ---- conv_w: WT[n][k] = bf16(W1[(n>=128?128:0)+k][n&127]), 256x128
    int i = (b - CB) * 1024 + tid;   // exactly 32768 over 32 blocks
    int n = i >> 7, k = i & 127;
    int src_row = ((n >> 7) << 7) + k;
    WT[n * 128 + k] = f2bf(W1[src_row * 128 + (n & 127)]);
  } else {
    // ---- crel: 8 rel per block
    float* rs  = (float*)smem;          // [8][128]
    float* red = rs + 1024;             // [8][128]
    int h = tid >> 7, d = tid & 127;
    int r = (b - CB - WB) * 8 + h;
    bool valid = r < n_rel;
    rs[h * 128 + d] = valid ? rel[r * 128 + d] : 0.f;
    __syncthreads();
    float acc = b1[d];
    for (int k = 0; k < 128; ++k)
      acc = fmaf(rs[h * 128 + k], W1[(256 + k) * 128 + d], acc);
    if (valid) Crelbf[r * 128 + d] = f2bf(acc);
    red[h * 128 + d] = acc * w2[d];
    __syncthreads();
    for (int s = 64; s > 0; s >>= 1) {
      if (d < s) red[h * 128 + d] += red[h * 128 + d + s];
      __syncthreads();
    }
    if (d == 0 && valid) pC[r] = red[h * 128];
  }
}

// ---------------------------------------------------------------
// D2 mid (1024t): msplitB_scan1 (blocks < SB) | gemm (4 sub-tiles
// per block). gemm stages WT into 64KB LDS once per block with an
// XOR swizzle (byte = n*256 + (seg*16 ^ ((n&7)<<4))) so B-fragment
// ds_read_b128s are ~2-way-conflict-free and L1 holds only x tiles.
// ---------------------------------------------------------------
__global__ __launch_bounds__(1024, 1) void mid(
    const float* __restrict__ x, const unsigned short* __restrict__ WT,
    const float* __restrict__ w2,
    unsigned short* __restrict__ Abf, unsigned short* __restrict__ Bmbf,
    float* __restrict__ pA, float* __restrict__ pB, int M,
    const unsigned int* __restrict__ cntg, unsigned short* __restrict__ p16,
    int* __restrict__ deg, int* __restrict__ off, int* __restrict__ partial,
    int n, int words, int C, int SB) {
  __shared__ __align__(16) unsigned char smem[65536];
  int b = blockIdx.x;
  int tid = threadIdx.x;

  if (b < SB) {
    // ---- msplitB + scan1: chunk-prefix p16, deg, block-local scan
    int* sdata = (int*)smem;
    int t = tid;
    int i = b * 1024 + t;
    int run = 0;
    if (i < n) {
      int w = i >> 2, sh = 8 * (i & 3);
      for (int c = 0; c < C; ++c) {
        unsigned int cw = cntg[(size_t)c * words + w];
        p16[(size_t)c * n + i] = (unsigned short)run;
        run += (int)((cw >> sh) & 0xFFu);
      }
      deg[i] = run;
    }
    int v = (i < n) ? run : 0;
    sdata[t] = v;
    __syncthreads();
    for (int s = 1; s < 1024; s <<= 1) {
      int add = (t >= s) ? sdata[t - s] : 0;
      __syncthreads();
      sdata[t] += add;
      __syncthreads();
    }
    if (i < n) off[i] = sdata[t] - v;   // block-local exclusive
    if (t == 1023) partial[b] = sdata[1023];
    return;
  }

  // ---- gemm: stage WT into swizzled LDS (all 1024 threads, coalesced)
  #pragma unroll
  for (int j = 0; j < 4; ++j) {
    int idx16 = j * 1024 + tid;          // 4096 16B segments (256 rows x 16)
    int nn  = idx16 >> 4;
    int seg = idx16 & 15;
    uint4 v = *(const uint4*)(WT + nn * 128 + seg * 8);
    *(uint4*)(smem + nn * 256 + ((seg * 16) ^ ((nn & 7) << 4))) = v;
  }
  __syncthreads();

  int sub = tid >> 8;
  int t   = tid & 255;
  int m0  = ((b - SB) * 4 + sub) * 64;
  if (m0 >= M) return;   // after the sync: safe

  int wave = t >> 6, lane = t & 63;
  int wm = wave >> 1, wn = wave & 1;
  int l15 = lane & 15, l4 = lane >> 4;

  f32x4 acc[2][8];
  #pragma unroll
  for (int mi = 0; mi < 2; ++mi)
    #pragma unroll
    for (int ni = 0; ni < 8; ++ni) acc[mi][ni] = (f32x4){0.f, 0.f, 0.f, 0.f};

  int arow0 = m0 + wm * 32 + l15;
  int arow1 = arow0 + 16;
  int ar0 = arow0 < M ? arow0 : M - 1;
  int ar1 = arow1 < M ? arow1 : M - 1;
  const float* xbase0 = x + (size_t)ar0 * 128 + l4 * 8;
  const float* xbase1 = x + (size_t)ar1 * 128 + l4 * 8;
  const int nrow = wn * 128 + l15;       // B-row base for this wave-half

  #pragma unroll
  for (int ks = 0; ks < 4; ++ks) {
    float4 a0lo = *(const float4*)(xbase0 + ks * 32);
    float4 a0hi = *(const float4*)(xbase0 + ks * 32 + 4);
    float4 a1lo = *(const float4*)(xbase1 + ks * 32);
    float4 a1hi = *(const float4*)(xbase1 + ks * 32 + 4);
    bf16x8 af0 = pack8(a0lo, a0hi);
    bf16x8 af1 = pack8(a1lo, a1hi);
    int segb = (l4 + ks * 4) * 16;       // k-segment byte offset (pre-swizzle)
    #pragma unroll
    for (int ni = 0; ni < 8; ++ni) {
      int nn = nrow + ni * 16;
      bf16x8 bf = *(const bf16x8*)(smem + nn * 256 + (segb ^ ((nn & 7) << 4)));
      acc[0][ni] = __builtin_amdgcn_mfma_f32_16x16x32_bf16(af0, bf, acc[0][ni], 0, 0, 0);
      acc[1][ni] = __builtin_amdgcn_mfma_f32_16x16x32_bf16(af1, bf, acc[1][ni], 0, 0, 0);
    }
  }

  // C/D layout: col = ni*16 + l15, row = m0 + wm*32 + mi*16 + l4*4 + r
  unsigned short* dstp = (wn == 0) ? Abf : Bmbf;
  #pragma unroll
  for (int mi = 0; mi < 2; ++mi) {
    #pragma unroll
    for (int ni = 0; ni < 8; ++ni) {
      int coll = ni * 16 + l15;
      #pragma unroll
      for (int r = 0; r < 4; ++r) {
        int row = m0 + wm * 32 + mi * 16 + l4 * 4 + r;
        if (row < M) dstp[(size_t)row * 128 + coll] = f2bf(acc[mi][ni][r]);
      }
    }
  }

  float w2c[8];
  #pragma unroll
  for (int ni = 0; ni < 8; ++ni) w2c[ni] = w2[ni * 16 + l15];
  float* pdst = (wn == 0) ? pA : pB;
  #pragma unroll
  for (int mi = 0; mi < 2; ++mi) {
    #pragma unroll
    for (int r = 0; r < 4; ++r) {
      float v = 0.f;
      #pragma unroll
      for (int ni = 0; ni < 8; ++ni) v = fmaf(acc[mi][ni][r], w2c[ni], v);
      v += __shfl_xor(v, 1, 64);
      v += __shfl_xor(v, 2, 64);
      v += __shfl_xor(v, 4, 64);
      v += __shfl_xor(v, 8, 64);
      if (l15 == 0) {
        int row = m0 + wm * 32 + mi * 16 + l4 * 4 + r;
        if (row < M) pdst[row] = v;
      }
    }
  }
}

// ---------------------------------------------------------------
// fill CSR slots, atomic-free, inline carry prefix:
// slot = off[dst] + carry[dst>>10] + p16[chunk][dst] + rank8[e]
// ---------------------------------------------------------------
__global__ __launch_bounds__(1024) void fill_perm(
    const int* __restrict__ srcs, const int* __restrict__ dsts,
    const int* __restrict__ types, const unsigned char* __restrict__ rank8,
    const int* __restrict__ off, const int* __restrict__ partial, int nb,
    const unsigned short* __restrict__ p16,
    unsigned int* __restrict__ stperm, int E, int n) {
  __shared__ int carryLUT[64];
  int tid = threadIdx.x;
  if (tid < 64) {
    int v = (tid < nb) ? partial[tid] : 0;
    int inc = v;
    #pragma unroll
    for (int s = 1; s < 64; s <<= 1) {
      int u = __shfl_up(inc, s, 64);
      if (tid >= s) inc += u;
    }
    carryLUT[tid] = inc - v;   // exclusive prefix
  }
  __syncthreads();
  int i = blockIdx.x * 1024 + tid;
  if (i < E) {
    int dn = dsts[i];
    int c = i >> CHUNK_SHIFT;
    int p = off[dn] + carryLUT[dn >> 10] + (int)p16[(size_t)c * n + dn] + (int)rank8[i];
    stperm[p] = (unsigned int)srcs[i] | ((unsigned int)types[i] << 16);
  }
}

// ---------------------------------------------------------------
// Aggregate: 4 nodes per wave (16 lanes x 8 cols, uint4 gathers).
// Inline carry prefix. Shift-free softmax.
// out[n] = lrelu( sum_e alpha_e(A[s]+Crel[t]) + B[n] )
// ---------------------------------------------------------------
__global__ __launch_bounds__(256) void aggregate(
    const int* __restrict__ off, const int* __restrict__ deg,
    const int* __restrict__ partial, int nb,
    const unsigned int* __restrict__ stperm,
    const float* __restrict__ pA, const float* __restrict__ pB,
    const float* __restrict__ pCg,
    const unsigned short* __restrict__ Abf,
    const unsigned short* __restrict__ Bmbf,
    const unsigned short* __restrict__ Crelbf,
    float* __restrict__ out, int n_nodes, int n_rel) {
  __shared__ float pCs[256];
  __shared__ int carryLUT[64];
  int tid = threadIdx.x;
  if (tid < 64) {
    int v = (tid < nb) ? partial[tid] : 0;
    int inc = v;
    #pragma unroll
    for (int s = 1; s < 64; s <<= 1) {
      int u = __shfl_up(inc, s, 64);
      if (tid >= s) inc += u;
    }
    carryLUT[tid] = inc - v;
  }
  for (int r = tid; r < n_rel; r += 256) pCs[r] = pCg[r];
  __syncthreads();

  int n = blockIdx.x * 16 + (tid >> 4);   // 16 nodes per block
  if (n >= n_nodes) return;
  int lane = tid & 15;
  int c8 = lane * 8;                       // 8 bf16 cols per lane
  int start = off[n] + carryLUT[n >> 10];
  int dcnt = deg[n];
  size_t obase = (size_t)n * 128 + c8;
  if (dcnt == 0) {
    *(float4*)(out + obase)     = (float4){0.f, 0.f, 0.f, 0.f};
    *(float4*)(out + obase + 4) = (float4){0.f, 0.f, 0.f, 0.f};
    return;
  }
  float pBn = pB[n];
  float a0 = 0.f, a1 = 0.f, a2 = 0.f, a3 = 0.f;
  float a4 = 0.f, a5 = 0.f, a6 = 0.f, a7 = 0.f, S = 0.f;
  int i = 0;
  for (; i + 4 <= dcnt; i += 4) {
    unsigned int st[4];
    #pragma unroll
    for (int j = 0; j < 4; ++j) st[j] = stperm[start + i + j];
    uint4 av[4], cv[4];
    float pa[4];
    #pragma unroll
    for (int j = 0; j < 4; ++j) {
      unsigned int s = st[j] & 0xFFFFu, t = st[j] >> 16;
      av[j] = *(const uint4*)(Abf + ((size_t)s << 7) + c8);
      cv[j] = *(const uint4*)(Crelbf + (t << 7) + c8);
      pa[j] = pA[s];
    }
    #pragma unroll
    for (int j = 0; j < 4; ++j) {
      float b = pa[j] + pBn + pCs[st[j] >> 16];
      b = b > 0.f ? b : SLOPE * b;
      float ex = __expf(b);
      S += ex;
      a0 = fmaf(ex, bflo(av[j].x) + bflo(cv[j].x), a0);
      a1 = fmaf(ex, bfhi(av[j].x) + bfhi(cv[j].x), a1);
      a2 = fmaf(ex, bflo(av[j].y) + bflo(cv[j].y), a2);
      a3 = fmaf(ex, bfhi(av[j].y) + bfhi(cv[j].y), a3);
      a4 = fmaf(ex, bflo(av[j].z) + bflo(cv[j].z), a4);
      a5 = fmaf(ex, bfhi(av[j].z) + bfhi(cv[j].z), a5);
      a6 = fmaf(ex, bflo(av[j].w) + bflo(cv[j].w), a6);
      a7 = fmaf(ex, bfhi(av[j].w) + bfhi(cv[j].w), a7);
    }
  }
  for (; i < dcnt; ++i) {
    unsigned int st = stperm[start + i];
    unsigned int s = st & 0xFFFFu, t = st >> 16;
    uint4 av = *(const uint4*)(Abf + ((size_t)s << 7) + c8);
    uint4 cv = *(const uint4*)(Crelbf + (t << 7) + c8);
    float b = pA[s] + pBn + pCs[t];
    b = b > 0.f ? b : SLOPE * b;
    float ex = __expf(b);
    S += ex;
    a0 = fmaf(ex, bflo(av.x) + bflo(cv.x), a0);
    a1 = fmaf(ex, bfhi(av.x) + bfhi(cv.x), a1);
    a2 = fmaf(ex, bflo(av.y) + bflo(cv.y), a2);
    a3 = fmaf(ex, bfhi(av.y) + bfhi(cv.y), a3);
    a4 = fmaf(ex, bflo(av.z) + bflo(cv.z), a4);
    a5 = fmaf(ex, bfhi(av.z) + bfhi(cv.z), a5);
    a6 = fmaf(ex, bflo(av.w) + bflo(cv.w), a6);
    a7 = fmaf(ex, bfhi(av.w) + bfhi(cv.w), a7);
  }
  float inv = 1.f / S;
  uint4 bm = *(const uint4*)(Bmbf + obase);
  float o0 = a0 * inv + bflo(bm.x);
  float o1 = a1 * inv + bfhi(bm.x);
  float o2 = a2 * inv + bflo(bm.y);
  float o3 = a3 * inv + bfhi(bm.y);
  float o4 = a4 * inv + bflo(bm.z);
  float o5 = a5 * inv + bfhi(bm.z);
  float o6 = a6 * inv + bflo(bm.w);
  float o7 = a7 * inv + bfhi(bm.w);
  o0 = o0 > 0.f ? o0 : SLOPE * o0;
  o1 = o1 > 0.f ? o1 : SLOPE * o1;
  o2 = o2 > 0.f ? o2 : SLOPE * o2;
  o3 = o3 > 0.f ? o3 : SLOPE * o3;
  o4 = o4 > 0.f ? o4 : SLOPE * o4;
  o5 = o5 > 0.f ? o5 : SLOPE * o5;
  o6 = o6 > 0.f ? o6 : SLOPE * o6;
  o7 = o7 > 0.f ? o7 : SLOPE * o7;
  *(float4*)(out + obase)     = (float4){o0, o1, o2, o3};
  *(float4*)(out + obase + 4) = (float4){o4, o5, o6, o7};
}

extern "C" void kernel_launch(void* const* d_in, const int* in_sizes, int n_in,
                              void* d_out, int out_size, void* d_ws, size_t ws_size,
                              hipStream_t stream) {
  const float* x    = (const float*)d_in[0];
  const float* rel  = (const float*)d_in[1];
  const float* W1   = (const float*)d_in[2];
  const float* b1   = (const float*)d_in[3];
  const float* w2   = (const float*)d_in[4];
  const int* edge_index = (const int*)d_in[5];
  const int* edge_type  = (const int*)d_in[6];

  int n_nodes = in_sizes[0] / 128;
  int n_rel   = in_sizes[1] / 128;
  int E       = in_sizes[6];
  const int* srcs = edge_index;
  const int* dsts = edge_index + E;
  float* out = (float*)d_out;

  int words = (n_nodes + 3) >> 2;
  int C     = (E + CHUNK_SZ - 1) >> CHUNK_SHIFT;

  auto align256 = [](size_t v) { return (v + 255) & ~(size_t)255; };
  char* ws = (char*)d_ws;
  unsigned short* WT     = (unsigned short*)ws; ws += align256(256 * 128 * 2);
  unsigned short* Abf    = (unsigned short*)ws; ws += align256((size_t)n_nodes * 128 * 2);
  unsigned short* Bmbf   = (unsigned short*)ws; ws += align256((size_t)n_nodes * 128 * 2);
  unsigned short* Crelbf = (unsigned short*)ws; ws += align256((size_t)n_rel * 128 * 2);
  float* pA    = (float*)ws; ws += align256((size_t)n_nodes * 4);
  float* pB    = (float*)ws; ws += align256((size_t)n_nodes * 4);
  float* pC    = (float*)ws; ws += align256((size_t)n_rel * 4);
  int* deg     = (int*)ws;   ws += align256((size_t)n_nodes * 4);
  int* off     = (int*)ws;   ws += align256((size_t)n_nodes * 4);
  int* partial = (int*)ws;   ws += align256(1024 * 4);
  unsigned int* cntg = (unsigned int*)ws;    ws += align256((size_t)C * words * 4);
  unsigned short* p16 = (unsigned short*)ws; ws += align256((size_t)C * n_nodes * 2);
  unsigned char* rank8 = (unsigned char*)ws; ws += align256((size_t)E);
  unsigned int* stperm = (unsigned int*)ws;  ws += align256((size_t)E * 4);

  // D1: msplitA | conv_w | crel
  int CB = C;                          // 62 msplitA blocks first
  int WB = 32;                         // conv_w: 32768 elems / 1024
  int RB = (n_rel + 7) / 8;            // crel blocks
  front<<<CB + WB + RB, 1024, 0, stream>>>(
      W1, WT, rel, b1, w2, Crelbf, pC, n_rel,
      dsts, cntg, rank8, E, words, CB, WB);

  // D2: msplitB_scan1 | gemm (4 sub-tiles per block, WT staged in LDS)
  int nb = (n_nodes + 1023) / 1024;    // must be <= 64
  int gB = (n_nodes + 63) / 64;
  int gB4 = (gB + 3) / 4;
  mid<<<nb + gB4, 1024, 0, stream>>>(
      x, WT, w2, Abf, Bmbf, pA, pB, n_nodes,
      cntg, p16, deg, off, partial, n_nodes, words, C, nb);

  // D3: fill CSR
  fill_perm<<<(E + 1023) / 1024, 1024, 0, stream>>>(
      srcs, dsts, edge_type, rank8, off, partial, nb, p16, stperm, E, n_nodes);

  // D4: aggregate
  aggregate<<<(n_nodes + 15) / 16, 256, 0, stream>>>(
      off, deg, partial, nb, stperm, pA, pB, pC, Abf, Bmbf, Crelbf,
      out, n_nodes, n_rel);
}